// Round 10
// baseline (169.976 us; speedup 1.0000x reference)
//
#include <hip/hip_runtime.h>
#include <stdint.h>

// PSROIPool: single fused kernel.
//
// One block per (b,c) plane:
//  1) issue async plane stage (global_load_lds w=16, 25.6 KB);
//  2) while stage is in flight: each wave scans its 256 rois, computes the
//     bin rectangle for THIS block's (ph,pw) only (~16 VALU/roi), and
//     wave-compacts batch-b matches into a private LDS segment via
//     __ballot + popcount prefix (no atomics, no cross-wave races);
//  3) one __syncthreads (drains stage vmcnt + LDS writes);
//  4) masked-float4 region sum from LDS, direct scatter write out[n*C+c].
//
// vs R8: removes prep+transpose launches and their graph gaps, the outT
// round-trip, global geometry tables, and all d_ws usage.
//
// Rounding semantics mirror the reference exactly (verified R1-R8, absmax 7.8e-3).

#define PSB 4
#define PSC 1029
#define PSH 80
#define PSW 80
#define PSCALE 0.0625f
#define PLANE_ELEMS (PSH * PSW)   // 6400
#define NMAX 1024

typedef __attribute__((address_space(3))) void lds_void;
typedef __attribute__((address_space(1))) void glob_void;

__global__ __launch_bounds__(256) void psroi_fused(
    const float* __restrict__ x,     // [B, C, H, W]
    const float* __restrict__ rois,  // [N, 5]
    float* __restrict__ out,         // [N, C]
    int N)
{
    const int blk = blockIdx.x;      // 0 .. B*C-1
    const int b   = blk / PSC;
    const int c   = blk - b * PSC;
    const int ph  = (c / 7) % 7;
    const int pw  = c % 7;

    __shared__ float    plane[PLANE_ELEMS];   // 25600 B
    __shared__ uint32_t geomL[NMAX];          //  4096 B  hs|he<<8|ws<<16|we<<24
    __shared__ uint16_t nL[NMAX];             //  2048 B  roi index

    const int tid  = threadIdx.x;
    const int lane = tid & 63;
    const int wv   = tid >> 6;                // wave 0..3, segment base wv*256

    // ---- 1) issue async plane stage (stays in flight through phase 2) ----
    {
        const float4* src4 = (const float4*)(x + ((size_t)b * PSC + c) * PLANE_ELEMS);
        float4* dst4 = (float4*)plane;
        #pragma unroll
        for (int i = 0; i < 6; ++i) {
            __builtin_amdgcn_global_load_lds(
                (const glob_void*)(src4 + tid + i * 256),
                (lds_void*)(dst4 + tid + i * 256), 16, 0, 0);
        }
        if (tid < 64) {   // wave-uniform branch (wave 0 only)
            __builtin_amdgcn_global_load_lds(
                (const glob_void*)(src4 + tid + 1536),
                (lds_void*)(dst4 + tid + 1536), 16, 0, 0);
        }
    }

    // ---- 2) scan + wave-compact rois of batch b (overlaps the stage) ----
    const float fph = (float)ph, fpw = (float)pw;
    int segCnt = 0;                            // wave-uniform running count
    const int rounds = (N + 255) >> 8;         // 4 for N=1024
    for (int j = 0; j < rounds; ++j) {
        int n = j * 256 + wv * 64 + lane;      // this wave scans a fixed 64-roi slice per round
        bool match = false;
        uint32_t pack = 0;
        if (n < N) {
            const float* r = rois + (size_t)n * 5;
            float rb = r[0], r1 = r[1], r2 = r[2], r3 = r[3], r4 = r[4];
            match = ((int)rb == b);

            float roi_sw = floorf(r1 + 0.5f) * PSCALE;
            float roi_sh = floorf(r2 + 0.5f) * PSCALE;
            float roi_ew = floorf(r3 + 1.5f) * PSCALE;   // rnd(x2 + 1.0)
            float roi_eh = floorf(r4 + 1.5f) * PSCALE;

            float bin_h = fmaxf(roi_eh - roi_sh, 0.1f) * (1.0f / 7.0f);
            float bin_w = fmaxf(roi_ew - roi_sw, 0.1f) * (1.0f / 7.0f);

            int hs = (int)fminf(fmaxf(floorf(fph * bin_h + roi_sh), 0.0f), (float)PSH);
            int he = (int)fminf(fmaxf(ceilf((fph + 1.0f) * bin_h + roi_sh), 0.0f), (float)PSH);
            int ws = (int)fminf(fmaxf(floorf(fpw * bin_w + roi_sw), 0.0f), (float)PSW);
            int we = (int)fminf(fmaxf(ceilf((fpw + 1.0f) * bin_w + roi_sw), 0.0f), (float)PSW);
            pack = (uint32_t)hs | ((uint32_t)he << 8) |
                   ((uint32_t)ws << 16) | ((uint32_t)we << 24);
        }
        unsigned long long mask = __ballot(match);
        int myoff = __popcll(mask & ((1ull << lane) - 1ull));
        if (match) {
            int s = wv * 256 + segCnt + myoff;
            geomL[s] = pack;
            nL[s]    = (uint16_t)n;
        }
        segCnt += (int)__popcll(mask);         // uniform across wave
    }

    __syncthreads();   // drains stage vmcnt + all LDS writes, then barrier

    // ---- 3) process this wave's own segment (no cross-wave reads) ----
    const float4* __restrict__ p4 = (const float4*)plane;

    for (int i = lane; i < segCnt; i += 64) {
        uint32_t g = geomL[wv * 256 + i];
        int n  = nL[wv * 256 + i];
        int hs = g & 0xFF, he = (g >> 8) & 0xFF;
        int ws = (g >> 16) & 0xFF, we = g >> 24;

        int a0   = ws >> 2;
        int nch  = (we > ws) ? (((we - 1) >> 2) - a0 + 1) : 0;   // 0..4
        int base = a0 * 4;

        // 0/1 masks for the up-to-4 float4 chunks covering [ws, we)
        float4 m0, m1, m2, m3;
        {
            int k;
            k = base;      m0.x = (k>=ws && k<we); k++; m0.y = (k>=ws && k<we); k++;
                           m0.z = (k>=ws && k<we); k++; m0.w = (k>=ws && k<we);
            k = base + 4;  m1.x = (k>=ws && k<we); k++; m1.y = (k>=ws && k<we); k++;
                           m1.z = (k>=ws && k<we); k++; m1.w = (k>=ws && k<we);
            k = base + 8;  m2.x = (k>=ws && k<we); k++; m2.y = (k>=ws && k<we); k++;
                           m2.z = (k>=ws && k<we); k++; m2.w = (k>=ws && k<we);
            k = base + 12; m3.x = (k>=ws && k<we); k++; m3.y = (k>=ws && k<we); k++;
                           m3.z = (k>=ws && k<we); k++; m3.w = (k>=ws && k<we);
        }

        float s = 0.0f;
        for (int h = hs; h < he; ++h) {
            const float4* rw = p4 + h * (PSW / 4) + a0;
            {
                float4 v = rw[0];
                s = fmaf(v.x, m0.x, s); s = fmaf(v.y, m0.y, s);
                s = fmaf(v.z, m0.z, s); s = fmaf(v.w, m0.w, s);
            }
            if (nch > 1) {
                float4 v = rw[1];
                s = fmaf(v.x, m1.x, s); s = fmaf(v.y, m1.y, s);
                s = fmaf(v.z, m1.z, s); s = fmaf(v.w, m1.w, s);
            }
            if (nch > 2) {
                float4 v = rw[2];
                s = fmaf(v.x, m2.x, s); s = fmaf(v.y, m2.y, s);
                s = fmaf(v.z, m2.z, s); s = fmaf(v.w, m2.w, s);
            }
            if (nch > 3) {
                float4 v = rw[3];
                s = fmaf(v.x, m3.x, s); s = fmaf(v.y, m3.y, s);
                s = fmaf(v.z, m3.z, s); s = fmaf(v.w, m3.w, s);
            }
        }

        int area = (he - hs) * (we - ws);
        out[(size_t)n * PSC + c] = (area > 0) ? s / (float)area : 0.0f;
    }
}

extern "C" void kernel_launch(void* const* d_in, const int* in_sizes, int n_in,
                              void* d_out, int out_size, void* d_ws, size_t ws_size,
                              hipStream_t stream) {
    const float* x    = (const float*)d_in[0];
    const float* rois = (const float*)d_in[1];
    float* out        = (float*)d_out;
    int N = in_sizes[1] / 5;   // 1024

    psroi_fused<<<PSB * PSC, 256, 0, stream>>>(x, rois, out, N);
}